// Round 11
// baseline (747.189 us; speedup 1.0000x reference)
//
#include <hip/hip_runtime.h>

typedef unsigned short u16;
typedef unsigned int   u32;

#define NB     512
#define NHEADS 8
#define HW     361
#define NPIX   184832      /* NB*HW */
#define NTOT   768
#define EPSBN  1e-5f
#define RS     0.17677669529663687f   /* sqrt(32)/32 */

typedef __bf16 bf16x8 __attribute__((ext_vector_type(8)));
typedef float  f32x4  __attribute__((ext_vector_type(4)));

__device__ __forceinline__ u16 f2bf(float f) {
  u32 u = __float_as_uint(f);
  u += 0x7fffu + ((u >> 16) & 1u);          // round-to-nearest-even
  return (u16)(u >> 16);
}
__device__ __forceinline__ float bf2f(u16 v) {
  return __uint_as_float(((u32)v) << 16);
}
__device__ __forceinline__ bf16x8 ldb8(const void* p) {
  return __builtin_bit_cast(bf16x8, *(const uint4*)p);
}

// ---------------- kernel 0: W -> bf16 [768][256]; bias; zero M rows + sx
__global__ __launch_bounds__(256) void k_prep(
    const float* __restrict__ Wq, const float* __restrict__ bq,
    const float* __restrict__ Wk, const float* __restrict__ bk,
    const float* __restrict__ Wv, const float* __restrict__ bv,
    u16* __restrict__ Wall, float* __restrict__ ball,
    float* __restrict__ Mg, float* __restrict__ sx) {
  const int n = blockIdx.x, t = threadIdx.x;
  const float* src; const float* bs; int r;
  if (n < 256)      { src = Wq; bs = bq; r = n; }
  else if (n < 512) { src = Wk; bs = bk; r = n - 256; }
  else              { src = Wv; bs = bv; r = n - 512; }
  Wall[n * 256 + t] = f2bf(src[r * 256 + t]);
  if (t == 0) ball[n] = bs[r];
  if (n < 256)  Mg[n * 256 + t] = 0.f;
  if (n == 256) sx[t] = 0.f;
}

// ---------------- kernel 1: moments M=XX^T + sx + xT bf16 cast (x read once)
// 256 blocks (2 images each) x 1024 thr (16 waves). LDS chunk [256c][64px] padded.
__global__ __launch_bounds__(1024) void k_mom(
    const float* __restrict__ x, u16* __restrict__ xT,
    float* __restrict__ Mg, float* __restrict__ sx) {
  __shared__ u16 Als[256 * 72];                    // 36,864 B; row stride 144B
  const int tid = threadIdx.x, g = blockIdx.x;
  const int lane = tid & 63, wv = tid >> 6;        // 16 waves
  const int pxl = lane;                            // px-in-chunk for staging
  const int l15 = lane & 15, kq = lane >> 4;
  const float* xb = x + (size_t)g * 2 * 256 * HW;  // 2 images per block

  float sxp[16];
  f32x4 acc[16];
  #pragma unroll
  for (int i = 0; i < 16; ++i) { sxp[i] = 0.f; acc[i] = (f32x4){0.f,0.f,0.f,0.f}; }

  #pragma unroll 1
  for (int ck = 0; ck < 12; ++ck) {
    const int pxg = ck * 64 + pxl;                 // 0..767 (722 valid)
    const bool inr = pxg < 722;
    const int img = (pxg >= HW) ? 1 : 0;
    int p = pxg - img * HW; if (p >= HW) p = HW - 1;
    const float* xpp = xb + (size_t)img * 256 * HW + p;
    #pragma unroll
    for (int i = 0; i < 16; ++i) {                 // c-set {wv, wv+16, ...}
      const int c = wv + i * 16;
      float v = inr ? xpp[(size_t)c * HW] : 0.f;
      sxp[i] += v;
      Als[c * 72 + pxl] = f2bf(v);
    }
    __syncthreads();
    // moments: wave strip c1 in [16wv,16wv+16), all 16 c2 frags, K=64
    #pragma unroll
    for (int ks = 0; ks < 2; ++ks) {
      bf16x8 a = ldb8(&Als[(wv * 16 + l15) * 72 + ks * 32 + kq * 8]);
      #pragma unroll
      for (int nc = 0; nc < 16; ++nc) {
        bf16x8 b = ldb8(&Als[(nc * 16 + l15) * 72 + ks * 32 + kq * 8]);
        acc[nc] = __builtin_amdgcn_mfma_f32_16x16x32_bf16(a, b, acc[nc], 0, 0, 0);
      }
    }
    // transpose-out: thread (px=pxl, c-block=wv*16..+15) -> xT row chunk (32B)
    if (inr) {
      u32 pk[8];
      #pragma unroll
      for (int i = 0; i < 8; ++i) {
        u16 lo = Als[(wv * 16 + 2 * i)     * 72 + pxl];
        u16 hi = Als[(wv * 16 + 2 * i + 1) * 72 + pxl];
        pk[i] = (u32)lo | ((u32)hi << 16);
      }
      uint4* dst = (uint4*)(xT + ((size_t)g * 722 + pxg) * 256 + wv * 16);
      dst[0] = make_uint4(pk[0], pk[1], pk[2], pk[3]);
      dst[1] = make_uint4(pk[4], pk[5], pk[6], pk[7]);
    }
    __syncthreads();
  }
  // sx: wave-reduce each of 16 partials, one atomic per (wave, i)
  #pragma unroll
  for (int i = 0; i < 16; ++i) {
    float v = sxp[i];
    v += __shfl_down(v, 32); v += __shfl_down(v, 16);
    v += __shfl_down(v, 8);  v += __shfl_down(v, 4);
    v += __shfl_down(v, 2);  v += __shfl_down(v, 1);
    if (lane == 0) atomicAdd(&sx[wv + i * 16], v);
  }
  // M: 64 atomics/thread; c1 = 16wv + kq*4 + j, c2 = nc*16 + l15
  #pragma unroll
  for (int nc = 0; nc < 16; ++nc)
    #pragma unroll
    for (int j = 0; j < 4; ++j)
      atomicAdd(&Mg[(wv * 16 + kq * 4 + j) * 256 + nc * 16 + l15], acc[nc][j]);
}

// ---------------- kernel 2: finalize BN via moments: s_all, t_all
__global__ __launch_bounds__(256) void k_stats2(
    const float* __restrict__ Mg, const float* __restrict__ sx,
    const float* __restrict__ Wq, const float* __restrict__ bq,
    const float* __restrict__ Wk, const float* __restrict__ bk,
    const float* __restrict__ Wv, const float* __restrict__ bv,
    const float* __restrict__ gQ, const float* __restrict__ betaQ,
    const float* __restrict__ gK, const float* __restrict__ betaK,
    const float* __restrict__ gV, const float* __restrict__ betaV,
    float* __restrict__ s_all, float* __restrict__ t_all) {
  __shared__ float ws[256];
  __shared__ float r1[4], r2[4];
  const int n = blockIdx.x, i = threadIdx.x;
  const int which = n >> 8, r = n & 255;
  const float* src = (which == 0) ? Wq : (which == 1) ? Wk : Wv;
  const float wi = src[r * 256 + i];
  ws[i] = wi;
  __syncthreads();
  float colsum = 0.f;
  #pragma unroll 4
  for (int j = 0; j < 256; ++j) colsum += Mg[j * 256 + i] * ws[j];   // coalesced cols
  float p1 = wi * sx[i];
  float p2 = wi * colsum;
  p1 += __shfl_down(p1, 32); p2 += __shfl_down(p2, 32);
  p1 += __shfl_down(p1, 16); p2 += __shfl_down(p2, 16);
  p1 += __shfl_down(p1, 8);  p2 += __shfl_down(p2, 8);
  p1 += __shfl_down(p1, 4);  p2 += __shfl_down(p2, 4);
  p1 += __shfl_down(p1, 2);  p2 += __shfl_down(p2, 2);
  p1 += __shfl_down(p1, 1);  p2 += __shfl_down(p2, 1);
  const int wv = i >> 6;
  if ((i & 63) == 0) { r1[wv] = p1; r2[wv] = p2; }
  __syncthreads();
  if (i == 0) {
    const float S1 = r1[0] + r1[1] + r1[2] + r1[3];
    const float S2 = r2[0] + r2[1] + r2[2] + r2[3];
    const float* bs = (which == 0) ? bq : (which == 1) ? bk : bv;
    const float* gs = (which == 0) ? gQ : (which == 1) ? gK : gV;
    const float* be = (which == 0) ? betaQ : (which == 1) ? betaK : betaV;
    const float b = bs[r];
    const float P = (float)NPIX;
    const float mean = (S1 + P * b) / P;
    const float Ey2  = (S2 + 2.f * b * S1 + P * b * b) / P;
    const float var  = Ey2 - mean * mean;
    const float s    = gs[r] * rsqrtf(var + EPSBN);
    s_all[n] = s;
    t_all[n] = be[r] - s * mean;
  }
}

// ---------------- kernel 3: fused QKV-GEMM + neighbor attention
// one block per (image, head); XCD-bijective decode keeps an image's 8 heads
// on one XCD (xT L2 reuse). GEMM A=W (M=96ch), B=xT (N=361px), both from L2.
__global__ __launch_bounds__(768) void k_fused(
    const u16* __restrict__ xT, const u16* __restrict__ Wall,
    const float* __restrict__ ball,
    const float* __restrict__ s_all, const float* __restrict__ t_all,
    const float* __restrict__ x, float* __restrict__ out) {
  __shared__ u16   P[96 * HW];                     // 69,312 B: Q rows 0-31,K 32-63,V 64-95
  __shared__ float aL[4 * HW];                     // 5,776 B
  __shared__ float stl[2 * 96];
  const int tid = threadIdx.x;
  const int wg  = blockIdx.x;
  const int bb  = (wg & 7) + 8 * (wg >> 6);        // all 8 heads of bb share XCD
  const int h   = (wg >> 3) & 7;

  if (tid < 96) {                                  // fold bias + rs into affine
    const int which = tid >> 5, c32 = tid & 31;
    const int n = which * 256 + h * 32 + c32;
    float s = s_all[n];
    float t = s * ball[n] + t_all[n];
    if (tid < 32) { s *= RS; t *= RS; }            // Q gets the 1/sqrt(32)*sqrt(att_c)
    stl[tid] = s; stl[96 + tid] = t;
  }
  __syncthreads();

  const int lane = tid & 63, wv = tid >> 6;        // 12 waves: px frag-cols {2wv,2wv+1}
  const int l15 = lane & 15, kq = lane >> 4;
  const u16* xTb = xT + (size_t)bb * HW * 256;
  const u16* wb  = Wall + (size_t)(h * 32 + l15) * 256 + kq * 8;

  f32x4 acc[6][2];
  #pragma unroll
  for (int f = 0; f < 6; ++f) { acc[f][0] = (f32x4){0.f,0.f,0.f,0.f}; acc[f][1] = (f32x4){0.f,0.f,0.f,0.f}; }

  #pragma unroll
  for (int ks = 0; ks < 8; ++ks) {
    const int ko = ks * 32;
    bf16x8 b0 = ldb8(xTb + (size_t)(wv * 32      + l15) * 256 + ko + kq * 8);
    bf16x8 b1 = ldb8(xTb + (size_t)(wv * 32 + 16 + l15) * 256 + ko + kq * 8);
    #pragma unroll
    for (int f = 0; f < 6; ++f) {
      bf16x8 a = ldb8(wb + (size_t)((f >> 1) * 256 + (f & 1) * 16) * 256 + ko);
      acc[f][0] = __builtin_amdgcn_mfma_f32_16x16x32_bf16(a, b0, acc[f][0], 0, 0, 0);
      acc[f][1] = __builtin_amdgcn_mfma_f32_16x16x32_bf16(a, b1, acc[f][1], 0, 0, 0);
    }
  }
  // epilogue: BN affine -> LDS [ch][px]; lanes are contiguous px
  #pragma unroll
  for (int f = 0; f < 6; ++f) {
    #pragma unroll
    for (int j = 0; j < 4; ++j) {
      const int ch = f * 16 + kq * 4 + j;
      const float s = stl[ch], t = stl[96 + ch];
      #pragma unroll
      for (int p2 = 0; p2 < 2; ++p2) {
        const int px = wv * 32 + p2 * 16 + l15;
        if (px < HW) P[ch * HW + px] = f2bf(s * acc[f][p2][j] + t);
      }
    }
  }
  __syncthreads();

  // phase 1: per-pixel logits + softmax (normalized Q,K straight dots)
  if (tid < HW) {
    const int px = tid;
    const int yy = px / 19, xx = px - yy * 19;
    const bool i0 = yy > 0, i1 = yy < 18, i2 = xx > 0, i3 = xx < 18;
    const int pn0 = i0 ? px - 19 : px, pn1 = i1 ? px + 19 : px;
    const int pn2 = i2 ? px - 1  : px, pn3 = i3 ? px + 1  : px;
    float l0 = 0.f, l1 = 0.f, l2 = 0.f, l3 = 0.f;
    #pragma unroll
    for (int c = 0; c < 32; ++c) {
      const float q = bf2f(P[c * HW + px]);
      const u16* Kr = &P[(32 + c) * HW];
      l0 += q * bf2f(Kr[pn0]); l1 += q * bf2f(Kr[pn1]);
      l2 += q * bf2f(Kr[pn2]); l3 += q * bf2f(Kr[pn3]);
    }
    l0 = i0 ? l0 : 0.f; l1 = i1 ? l1 : 0.f;
    l2 = i2 ? l2 : 0.f; l3 = i3 ? l3 : 0.f;
    const float mx = fmaxf(fmaxf(l0, l1), fmaxf(l2, l3));
    const float e0 = __expf(l0 - mx), e1 = __expf(l1 - mx);
    const float e2 = __expf(l2 - mx), e3 = __expf(l3 - mx);
    const float inv = 1.f / (e0 + e1 + e2 + e3);
    aL[0 * HW + px] = i0 ? e0 * inv : 0.f;
    aL[1 * HW + px] = i1 ? e1 * inv : 0.f;
    aL[2 * HW + px] = i2 ? e2 * inv : 0.f;
    aL[3 * HW + px] = i3 ? e3 * inv : 0.f;
  }
  __syncthreads();

  // phase 2: (px, oc-half) threads; ReLU + residual
  if (tid < 2 * HW) {
    const int px  = (tid < HW) ? tid : tid - HW;
    const int oc0 = (tid < HW) ? 0 : 16;
    const int yy = px / 19, xx = px - yy * 19;
    const int pn0 = (yy > 0)  ? px - 19 : px, pn1 = (yy < 18) ? px + 19 : px;
    const int pn2 = (xx > 0)  ? px - 1  : px, pn3 = (xx < 18) ? px + 1  : px;
    const float a0 = aL[0 * HW + px], a1 = aL[1 * HW + px];
    const float a2 = aL[2 * HW + px], a3 = aL[3 * HW + px];
    const size_t gb = ((size_t)bb * 256 + h * 32 + oc0) * HW + px;
    #pragma unroll
    for (int o = 0; o < 16; ++o) {
      const u16* Vr = &P[(64 + oc0 + o) * HW];
      float v = a0 * bf2f(Vr[pn0]) + a1 * bf2f(Vr[pn1])
              + a2 * bf2f(Vr[pn2]) + a3 * bf2f(Vr[pn3]);
      v = fmaxf(v, 0.f);
      const size_t gg = gb + (size_t)o * HW;
      out[gg] = v + x[gg];
    }
  }
}

// ---------------- workspace layout
constexpr size_t OFF_XT    = 0;
constexpr size_t SZ_XT     = (size_t)NPIX * 512 + 16384;   // + pad for px>=361 frag reads
constexpr size_t OFF_WALL  = OFF_XT + SZ_XT;
constexpr size_t SZ_WALL   = (size_t)NTOT * 512;
constexpr size_t OFF_BALL  = OFF_WALL + SZ_WALL;
constexpr size_t OFF_M     = OFF_BALL + NTOT * 4;
constexpr size_t SZ_M      = 256 * 256 * 4;
constexpr size_t OFF_SX    = OFF_M + SZ_M;
constexpr size_t OFF_SALL  = OFF_SX + 256 * 4;
constexpr size_t OFF_TALL  = OFF_SALL + NTOT * 4;
constexpr size_t WS_NEEDED = OFF_TALL + NTOT * 4;

extern "C" void kernel_launch(void* const* d_in, const int* in_sizes, int n_in,
                              void* d_out, int out_size, void* d_ws, size_t ws_size,
                              hipStream_t stream) {
  (void)in_sizes; (void)n_in; (void)out_size;
  if (ws_size < WS_NEEDED) return;

  const float* x     = (const float*)d_in[0];
  const float* Wq    = (const float*)d_in[1];
  const float* bq    = (const float*)d_in[2];
  const float* Wk    = (const float*)d_in[3];
  const float* bk    = (const float*)d_in[4];
  const float* Wv    = (const float*)d_in[5];
  const float* bv    = (const float*)d_in[6];
  const float* gQ    = (const float*)d_in[7];
  const float* betaQ = (const float*)d_in[8];
  const float* gK    = (const float*)d_in[9];
  const float* betaK = (const float*)d_in[10];
  const float* gV    = (const float*)d_in[11];
  const float* betaV = (const float*)d_in[12];
  float* out = (float*)d_out;

  char* wsp = (char*)d_ws;
  u16*   xT    = (u16*)(wsp + OFF_XT);
  u16*   Wall  = (u16*)(wsp + OFF_WALL);
  float* ball  = (float*)(wsp + OFF_BALL);
  float* Mg    = (float*)(wsp + OFF_M);
  float* sx    = (float*)(wsp + OFF_SX);
  float* s_all = (float*)(wsp + OFF_SALL);
  float* t_all = (float*)(wsp + OFF_TALL);

  k_prep<<<NTOT, 256, 0, stream>>>(Wq, bq, Wk, bk, Wv, bv, Wall, ball, Mg, sx);
  k_mom<<<256, 1024, 0, stream>>>(x, xT, Mg, sx);
  k_stats2<<<NTOT, 256, 0, stream>>>(Mg, sx, Wq, bq, Wk, bk, Wv, bv,
                                     gQ, betaQ, gK, betaK, gV, betaV, s_all, t_all);
  k_fused<<<NB * NHEADS, 768, 0, stream>>>(xT, Wall, ball, s_all, t_all, x, out);
}

// Round 12
// 667.641 us; speedup vs baseline: 1.1191x; 1.1191x over previous
//
#include <hip/hip_runtime.h>

typedef unsigned short u16;
typedef unsigned int   u32;

#define NB     512
#define NHEADS 8
#define HW     361
#define NPIX   184832      /* NB*HW */
#define NTOT   768
#define EPSBN  1e-5f
#define RS     0.17677669529663687f   /* sqrt(32)/32 */

typedef __bf16 bf16x8 __attribute__((ext_vector_type(8)));
typedef float  f32x4  __attribute__((ext_vector_type(4)));

__device__ __forceinline__ u16 f2bf(float f) {
  u32 u = __float_as_uint(f);
  u += 0x7fffu + ((u >> 16) & 1u);          // round-to-nearest-even
  return (u16)(u >> 16);
}
__device__ __forceinline__ float bf2f(u16 v) {
  return __uint_as_float(((u32)v) << 16);
}
__device__ __forceinline__ bf16x8 ldb8(const void* p) {
  return __builtin_bit_cast(bf16x8, *(const uint4*)p);
}

// ---------------- kernel 0: W -> bf16 [768][256]; bias; zero M rows + sx
__global__ __launch_bounds__(256) void k_prep(
    const float* __restrict__ Wq, const float* __restrict__ bq,
    const float* __restrict__ Wk, const float* __restrict__ bk,
    const float* __restrict__ Wv, const float* __restrict__ bv,
    u16* __restrict__ Wall, float* __restrict__ ball,
    float* __restrict__ Mg, float* __restrict__ sx) {
  const int n = blockIdx.x, t = threadIdx.x;
  const float* src; const float* bs; int r;
  if (n < 256)      { src = Wq; bs = bq; r = n; }
  else if (n < 512) { src = Wk; bs = bk; r = n - 256; }
  else              { src = Wv; bs = bv; r = n - 512; }
  Wall[n * 256 + t] = f2bf(src[r * 256 + t]);
  if (t == 0) ball[n] = bs[r];
  if (n < 256)  Mg[n * 256 + t] = 0.f;
  if (n == 256) sx[t] = 0.f;
}

// ---------------- kernel 1: moments M=XX^T + sx + xT bf16 cast (x read once)
// 512 blocks (1 image) x 1024 thr (16 waves). LDS chunk [256c][64px] padded.
__global__ __launch_bounds__(1024) void k_mom(
    const float* __restrict__ x, u16* __restrict__ xT,
    float* __restrict__ Mg, float* __restrict__ sx) {
  __shared__ u16 Als[256 * 72];                    // 36,864 B; row stride 144B
  const int tid = threadIdx.x, g = blockIdx.x;     // g = image
  const int lane = tid & 63, wv = tid >> 6;        // 16 waves
  const int pxl = lane;                            // px-in-chunk for staging
  const int l15 = lane & 15, kq = lane >> 4;
  const float* xb = x + (size_t)g * 256 * HW;

  float sxp[16];
  f32x4 acc[16];
  #pragma unroll
  for (int i = 0; i < 16; ++i) { sxp[i] = 0.f; acc[i] = (f32x4){0.f,0.f,0.f,0.f}; }

  #pragma unroll 1
  for (int ck = 0; ck < 6; ++ck) {
    const int pxg = ck * 64 + pxl;                 // 0..383 (361 valid)
    const bool inr = pxg < HW;
    const int p = inr ? pxg : HW - 1;
    const float* xpp = xb + p;
    #pragma unroll
    for (int i = 0; i < 16; ++i) {                 // c-set {wv, wv+16, ...}
      const int c = wv + i * 16;
      float v = inr ? xpp[(size_t)c * HW] : 0.f;
      sxp[i] += v;
      Als[c * 72 + pxl] = f2bf(v);
    }
    __syncthreads();
    // moments: wave strip c1 in [16wv,16wv+16), all 16 c2 frags, K=64
    #pragma unroll
    for (int ks = 0; ks < 2; ++ks) {
      bf16x8 a = ldb8(&Als[(wv * 16 + l15) * 72 + ks * 32 + kq * 8]);
      #pragma unroll
      for (int nc = 0; nc < 16; ++nc) {
        bf16x8 b = ldb8(&Als[(nc * 16 + l15) * 72 + ks * 32 + kq * 8]);
        acc[nc] = __builtin_amdgcn_mfma_f32_16x16x32_bf16(a, b, acc[nc], 0, 0, 0);
      }
    }
    // transpose-out: thread (px=pxl, c-block=wv*16..+15) -> xT row chunk (32B)
    if (inr) {
      u32 pk[8];
      #pragma unroll
      for (int i = 0; i < 8; ++i) {
        u16 lo = Als[(wv * 16 + 2 * i)     * 72 + pxl];
        u16 hi = Als[(wv * 16 + 2 * i + 1) * 72 + pxl];
        pk[i] = (u32)lo | ((u32)hi << 16);
      }
      uint4* dst = (uint4*)(xT + ((size_t)g * HW + pxg) * 256 + wv * 16);
      dst[0] = make_uint4(pk[0], pk[1], pk[2], pk[3]);
      dst[1] = make_uint4(pk[4], pk[5], pk[6], pk[7]);
    }
    __syncthreads();
  }
  // sx: wave-reduce each of 16 partials, one atomic per (wave, i)
  #pragma unroll
  for (int i = 0; i < 16; ++i) {
    float v = sxp[i];
    v += __shfl_down(v, 32); v += __shfl_down(v, 16);
    v += __shfl_down(v, 8);  v += __shfl_down(v, 4);
    v += __shfl_down(v, 2);  v += __shfl_down(v, 1);
    if (lane == 0) atomicAdd(&sx[wv + i * 16], v);
  }
  // M: 64 atomics/thread; c1 = 16wv + kq*4 + j, c2 = nc*16 + l15
  #pragma unroll
  for (int nc = 0; nc < 16; ++nc)
    #pragma unroll
    for (int j = 0; j < 4; ++j)
      atomicAdd(&Mg[(wv * 16 + kq * 4 + j) * 256 + nc * 16 + l15], acc[nc][j]);
}

// ---------------- kernel 2: finalize BN via moments: s_all, t_all
__global__ __launch_bounds__(256) void k_stats2(
    const float* __restrict__ Mg, const float* __restrict__ sx,
    const float* __restrict__ Wq, const float* __restrict__ bq,
    const float* __restrict__ Wk, const float* __restrict__ bk,
    const float* __restrict__ Wv, const float* __restrict__ bv,
    const float* __restrict__ gQ, const float* __restrict__ betaQ,
    const float* __restrict__ gK, const float* __restrict__ betaK,
    const float* __restrict__ gV, const float* __restrict__ betaV,
    float* __restrict__ s_all, float* __restrict__ t_all) {
  __shared__ float ws[256];
  __shared__ float r1[4], r2[4];
  const int n = blockIdx.x, i = threadIdx.x;
  const int which = n >> 8, r = n & 255;
  const float* src = (which == 0) ? Wq : (which == 1) ? Wk : Wv;
  const float wi = src[r * 256 + i];
  ws[i] = wi;
  __syncthreads();
  float colsum = 0.f;
  #pragma unroll 4
  for (int j = 0; j < 256; ++j) colsum += Mg[j * 256 + i] * ws[j];   // coalesced cols
  float p1 = wi * sx[i];
  float p2 = wi * colsum;
  p1 += __shfl_down(p1, 32); p2 += __shfl_down(p2, 32);
  p1 += __shfl_down(p1, 16); p2 += __shfl_down(p2, 16);
  p1 += __shfl_down(p1, 8);  p2 += __shfl_down(p2, 8);
  p1 += __shfl_down(p1, 4);  p2 += __shfl_down(p2, 4);
  p1 += __shfl_down(p1, 2);  p2 += __shfl_down(p2, 2);
  p1 += __shfl_down(p1, 1);  p2 += __shfl_down(p2, 1);
  const int wv = i >> 6;
  if ((i & 63) == 0) { r1[wv] = p1; r2[wv] = p2; }
  __syncthreads();
  if (i == 0) {
    const float S1 = r1[0] + r1[1] + r1[2] + r1[3];
    const float S2 = r2[0] + r2[1] + r2[2] + r2[3];
    const float* bs = (which == 0) ? bq : (which == 1) ? bk : bv;
    const float* gs = (which == 0) ? gQ : (which == 1) ? gK : gV;
    const float* be = (which == 0) ? betaQ : (which == 1) ? betaK : betaV;
    const float b = bs[r];
    const float P = (float)NPIX;
    const float mean = (S1 + P * b) / P;
    const float Ey2  = (S2 + 2.f * b * S1 + P * b * b) / P;
    const float var  = Ey2 - mean * mean;
    const float s    = gs[r] * rsqrtf(var + EPSBN);
    s_all[n] = s;
    t_all[n] = be[r] - s * mean;
  }
}

// ---------------- kernel 3: fused QKV-GEMM + neighbor attention
// one block per (image, head); XCD-bijective decode keeps an image's 8 heads
// on one XCD. W staged in LDS (rotated); xT B-frags batch-preloaded from L2.
__global__ __launch_bounds__(768) void k_fused(
    const u16* __restrict__ xT, const u16* __restrict__ Wall,
    const float* __restrict__ ball,
    const float* __restrict__ s_all, const float* __restrict__ t_all,
    const float* __restrict__ x, float* __restrict__ out) {
  __shared__ u16   Wl[96 * 256];                   // 48 KB, rotated rows
  __shared__ u16   P[96 * HW];                     // 69,312 B
  __shared__ float aL[4 * HW];                     // 5,776 B
  __shared__ float stl[2 * 96];
  const int tid = threadIdx.x;
  const int wg  = blockIdx.x;
  const int bb  = (wg & 7) + 8 * (wg >> 6);        // all 8 heads of bb share XCD
  const int h   = (wg >> 3) & 7;

  if (tid < 96) {                                  // fold bias + rs into affine
    const int which = tid >> 5, c32 = tid & 31;
    const int n = which * 256 + h * 32 + c32;
    float s = s_all[n];
    float t = s * ball[n] + t_all[n];
    if (tid < 32) { s *= RS; t *= RS; }            // Q gets sqrt(att_c)/att_c
    stl[tid] = s; stl[96 + tid] = t;
  }
  // stage W head-slice into LDS, rotation-swizzled (granule g -> slot (g+4*(row&7))&31)
  #pragma unroll
  for (int i = 0; i < 4; ++i) {
    const int gi = tid + i * 768;                  // 0..3071
    const int lr = gi >> 5, gg = gi & 31;
    const int which = lr >> 5, c32 = lr & 31;
    uint4 v = *(const uint4*)(Wall + (size_t)(which * 256 + h * 32 + c32) * 256 + gg * 8);
    const int slot = (gg + 4 * (lr & 7)) & 31;
    *(uint4*)((char*)Wl + lr * 512 + slot * 16) = v;
  }
  __syncthreads();

  const int lane = tid & 63, wv = tid >> 6;        // 12 waves: px frag-cols {2wv,2wv+1}
  const int l15 = lane & 15, kq = lane >> 4;
  const u16* xTb = xT + (size_t)bb * HW * 256;

  // batch-preload all 16 B-frags (xT, L2) into registers
  uint4 bfr[16];
  #pragma unroll
  for (int ks = 0; ks < 8; ++ks) {
    bfr[2 * ks]     = *(const uint4*)(xTb + (size_t)(wv * 32      + l15) * 256 + ks * 32 + kq * 8);
    bfr[2 * ks + 1] = *(const uint4*)(xTb + (size_t)(wv * 32 + 16 + l15) * 256 + ks * 32 + kq * 8);
  }

  f32x4 acc[6][2];
  #pragma unroll
  for (int f = 0; f < 6; ++f) { acc[f][0] = (f32x4){0.f,0.f,0.f,0.f}; acc[f][1] = (f32x4){0.f,0.f,0.f,0.f}; }

  #pragma unroll
  for (int ks = 0; ks < 8; ++ks) {
    bf16x8 b0 = __builtin_bit_cast(bf16x8, bfr[2 * ks]);
    bf16x8 b1 = __builtin_bit_cast(bf16x8, bfr[2 * ks + 1]);
    const int slot = ((ks * 4 + kq + 4 * (l15 & 7)) & 31) * 16;
    #pragma unroll
    for (int f = 0; f < 6; ++f) {
      const int lr = (f >> 1) * 32 + (f & 1) * 16 + l15;
      bf16x8 a = ldb8((const char*)Wl + lr * 512 + slot);
      acc[f][0] = __builtin_amdgcn_mfma_f32_16x16x32_bf16(a, b0, acc[f][0], 0, 0, 0);
      acc[f][1] = __builtin_amdgcn_mfma_f32_16x16x32_bf16(a, b1, acc[f][1], 0, 0, 0);
    }
  }
  // epilogue: BN affine -> LDS [ch][px]; lanes are contiguous px
  #pragma unroll
  for (int f = 0; f < 6; ++f) {
    #pragma unroll
    for (int j = 0; j < 4; ++j) {
      const int ch = f * 16 + kq * 4 + j;
      const float s = stl[ch], t = stl[96 + ch];
      #pragma unroll
      for (int p2 = 0; p2 < 2; ++p2) {
        const int px = wv * 32 + p2 * 16 + l15;
        if (px < HW) P[ch * HW + px] = f2bf(s * acc[f][p2][j] + t);
      }
    }
  }
  __syncthreads();

  // phase 1: per-pixel logits + softmax (normalized Q,K straight dots)
  if (tid < HW) {
    const int px = tid;
    const int yy = px / 19, xx = px - yy * 19;
    const bool i0 = yy > 0, i1 = yy < 18, i2 = xx > 0, i3 = xx < 18;
    const int pn0 = i0 ? px - 19 : px, pn1 = i1 ? px + 19 : px;
    const int pn2 = i2 ? px - 1  : px, pn3 = i3 ? px + 1  : px;
    float l0 = 0.f, l1 = 0.f, l2 = 0.f, l3 = 0.f;
    #pragma unroll
    for (int c = 0; c < 32; ++c) {
      const float q = bf2f(P[c * HW + px]);
      const u16* Kr = &P[(32 + c) * HW];
      l0 += q * bf2f(Kr[pn0]); l1 += q * bf2f(Kr[pn1]);
      l2 += q * bf2f(Kr[pn2]); l3 += q * bf2f(Kr[pn3]);
    }
    l0 = i0 ? l0 : 0.f; l1 = i1 ? l1 : 0.f;
    l2 = i2 ? l2 : 0.f; l3 = i3 ? l3 : 0.f;
    const float mx = fmaxf(fmaxf(l0, l1), fmaxf(l2, l3));
    const float e0 = __expf(l0 - mx), e1 = __expf(l1 - mx);
    const float e2 = __expf(l2 - mx), e3 = __expf(l3 - mx);
    const float inv = 1.f / (e0 + e1 + e2 + e3);
    aL[0 * HW + px] = i0 ? e0 * inv : 0.f;
    aL[1 * HW + px] = i1 ? e1 * inv : 0.f;
    aL[2 * HW + px] = i2 ? e2 * inv : 0.f;
    aL[3 * HW + px] = i3 ? e3 * inv : 0.f;
  }
  __syncthreads();

  // phase 2: (px, oc-half) threads; ReLU + residual
  if (tid < 2 * HW) {
    const int px  = (tid < HW) ? tid : tid - HW;
    const int oc0 = (tid < HW) ? 0 : 16;
    const int yy = px / 19, xx = px - yy * 19;
    const int pn0 = (yy > 0)  ? px - 19 : px, pn1 = (yy < 18) ? px + 19 : px;
    const int pn2 = (xx > 0)  ? px - 1  : px, pn3 = (xx < 18) ? px + 1  : px;
    const float a0 = aL[0 * HW + px], a1 = aL[1 * HW + px];
    const float a2 = aL[2 * HW + px], a3 = aL[3 * HW + px];
    const size_t gb = ((size_t)bb * 256 + h * 32 + oc0) * HW + px;
    #pragma unroll
    for (int o = 0; o < 16; ++o) {
      const u16* Vr = &P[(64 + oc0 + o) * HW];
      float v = a0 * bf2f(Vr[pn0]) + a1 * bf2f(Vr[pn1])
              + a2 * bf2f(Vr[pn2]) + a3 * bf2f(Vr[pn3]);
      v = fmaxf(v, 0.f);
      const size_t gg = gb + (size_t)o * HW;
      out[gg] = v + x[gg];
    }
  }
}

// ---------------- workspace layout
constexpr size_t OFF_XT    = 0;
constexpr size_t SZ_XT     = (size_t)NPIX * 512 + 16384;   // + pad for px>=361 frag reads
constexpr size_t OFF_WALL  = OFF_XT + SZ_XT;
constexpr size_t SZ_WALL   = (size_t)NTOT * 512;
constexpr size_t OFF_BALL  = OFF_WALL + SZ_WALL;
constexpr size_t OFF_M     = OFF_BALL + NTOT * 4;
constexpr size_t SZ_M      = 256 * 256 * 4;
constexpr size_t OFF_SX    = OFF_M + SZ_M;
constexpr size_t OFF_SALL  = OFF_SX + 256 * 4;
constexpr size_t OFF_TALL  = OFF_SALL + NTOT * 4;
constexpr size_t WS_NEEDED = OFF_TALL + NTOT * 4;

extern "C" void kernel_launch(void* const* d_in, const int* in_sizes, int n_in,
                              void* d_out, int out_size, void* d_ws, size_t ws_size,
                              hipStream_t stream) {
  (void)in_sizes; (void)n_in; (void)out_size;
  if (ws_size < WS_NEEDED) return;

  const float* x     = (const float*)d_in[0];
  const float* Wq    = (const float*)d_in[1];
  const float* bq    = (const float*)d_in[2];
  const float* Wk    = (const float*)d_in[3];
  const float* bk    = (const float*)d_in[4];
  const float* Wv    = (const float*)d_in[5];
  const float* bv    = (const float*)d_in[6];
  const float* gQ    = (const float*)d_in[7];
  const float* betaQ = (const float*)d_in[8];
  const float* gK    = (const float*)d_in[9];
  const float* betaK = (const float*)d_in[10];
  const float* gV    = (const float*)d_in[11];
  const float* betaV = (const float*)d_in[12];
  float* out = (float*)d_out;

  char* wsp = (char*)d_ws;
  u16*   xT    = (u16*)(wsp + OFF_XT);
  u16*   Wall  = (u16*)(wsp + OFF_WALL);
  float* ball  = (float*)(wsp + OFF_BALL);
  float* Mg    = (float*)(wsp + OFF_M);
  float* sx    = (float*)(wsp + OFF_SX);
  float* s_all = (float*)(wsp + OFF_SALL);
  float* t_all = (float*)(wsp + OFF_TALL);

  k_prep<<<NTOT, 256, 0, stream>>>(Wq, bq, Wk, bk, Wv, bv, Wall, ball, Mg, sx);
  k_mom<<<NB, 1024, 0, stream>>>(x, xT, Mg, sx);
  k_stats2<<<NTOT, 256, 0, stream>>>(Mg, sx, Wq, bq, Wk, bk, Wv, bv,
                                     gQ, betaQ, gK, betaK, gV, betaV, s_all, t_all);
  k_fused<<<NB * NHEADS, 768, 0, stream>>>(xT, Wall, ball, s_all, t_all, x, out);
}